// Round 6
// baseline (145.836 us; speedup 1.0000x reference)
//
#include <hip/hip_runtime.h>
#include <hip/hip_bf16.h>

// SelectSparse (PyG TopKPooling select). x [100000,256] f32 (dtype probed),
// W [256], b [1], batch unused. G=1000 graphs x 100 nodes, k=50.
// out (f32, concat): node_index[50000] ++ cluster_index[50000] ++ weight[50000].
//
// R12: 2 graphs/block. Ledger after R11: 145.7us = ~121.2us unconditional ws
// re-poison fills (2x400MB, harness-fixed) + ~24.5us fused kernel (floor
// ~19-20us). Remaining cost is lockstep-serial phases: select tail with no
// loads in flight, per-block probe/W overhead x1000, and hipcc's
// vmcnt(0)-before-barrier drain. This round: 500 blocks x 2 graphs, per-wave
// continuous 50-row ping-pong load stream, merges write to scA/scB dual LDS
// buffers (no intermediate barriers), ONE __syncthreads, then parallel
// selects (tid 0..99 -> graph A, tid 128..227 -> graph B).
// Predicted: kernel ~24.5 -> ~21, dur_us 145.7 -> ~142.

#define NPG   100   // nodes per graph
#define DIM   256   // in channels
#define KSEL  50    // ceil(0.5 * 100)
#define ROWS_PER_WAVE 25    // per graph: 100 rows / 4 waves

typedef float vfloat4 __attribute__((ext_vector_type(4)));

static __device__ __forceinline__ float bf2f(unsigned short s) {
    union { unsigned int u; float f; } v;
    v.u = ((unsigned int)s) << 16;
    return v.f;
}

// x ~ N(0,1): a bf16 buffer decodes every uint16 to |v|<64; an f32 buffer's
// even uint16s are random mantissa bits (P[all 64 probes < 64] ~ 5e-19).
// Uniform across threads/blocks, one cache line, L2-hot after block 0.
static __device__ __forceinline__ bool probe_f32(const void* xv) {
    const unsigned short* xu = (const unsigned short*)xv;
    bool f32 = false;
    #pragma unroll
    for (int i = 0; i < 64; ++i) {
        const float v = bf2f(xu[2 * i]);
        if (!(v > -64.0f && v < 64.0f)) f32 = true;
    }
    return f32;
}

// Merge two rows' per-lane partials: after cascading mask=1,2,4 the register
// holds row (lane&7)'s partial over the 8-lane group {x : x == lane (mod 8)}.
static __device__ __forceinline__ float mergepair(float a, float b, int lane, int mask) {
    const bool hi = (lane & mask) != 0;
    const float u = hi ? b : a;
    const float w = hi ? a : b;
    return u + __shfl_xor(w, mask, 64);
}

// 8 per-lane row-partials -> full row sums; lane l ends holding the complete
// sum of row (l&7), replicated. 7 merge shfls + 3 butterfly shfls.
static __device__ __forceinline__ float merge8(const float* p, int lane) {
    float m01 = mergepair(p[0], p[1], lane, 1);
    float m23 = mergepair(p[2], p[3], lane, 1);
    float m45 = mergepair(p[4], p[5], lane, 1);
    float m67 = mergepair(p[6], p[7], lane, 1);
    float m03 = mergepair(m01, m23, lane, 2);
    float m47 = mergepair(m45, m67, lane, 2);
    float m   = mergepair(m03, m47, lane, 4);
    m += __shfl_xor(m, 8, 64);
    m += __shfl_xor(m, 16, 64);
    m += __shfl_xor(m, 32, 64);
    return m;
}

static __device__ __forceinline__ void load8(vfloat4* u, const vfloat4* base, int row0) {
    #pragma unroll
    for (int i = 0; i < 8; ++i)
        u[i] = __builtin_nontemporal_load(base + (size_t)(row0 + i) * (DIM / 4));
}

static __device__ __forceinline__ void dot8(float* p, const vfloat4* u,
                                            float w0, float w1, float w2, float w3) {
    #pragma unroll
    for (int i = 0; i < 8; ++i)
        p[i] = u[i].x * w0 + u[i].y * w1 + u[i].z * w2 + u[i].w * w3;
}

// ---------------- Fused kernel: GEMV scores + per-graph top-50 -------------
__global__ __launch_bounds__(256, 4) void fused_select_kernel(
    const void* __restrict__ xv,
    const void* __restrict__ Wv,
    const void* __restrict__ bv,
    void* __restrict__ outv,
    int num_graphs)
{
    __shared__ float w_sh[DIM];
    __shared__ float scA[NPG];
    __shared__ float scB[NPG];

    const int tid  = threadIdx.x;
    const int wave = tid >> 6;
    const int lane = tid & 63;

    const int gA   = 2 * blockIdx.x;
    const int gB   = gA + 1;
    const bool hasB = (gB < num_graphs);

    const bool f32 = probe_f32(xv);

    if (f32) w_sh[tid] = ((const float*)Wv)[tid];
    else     w_sh[tid] = bf2f(((const unsigned short*)Wv)[tid]);
    __syncthreads();

    const float bval = f32 ? ((const float*)bv)[0]
                           : bf2f(((const unsigned short*)bv)[0]);
    const float wl0 = w_sh[lane * 4 + 0];
    const float wl1 = w_sh[lane * 4 + 1];
    const float wl2 = w_sh[lane * 4 + 2];
    const float wl3 = w_sh[lane * 4 + 3];

    // This wave's rows within each graph: rbase .. rbase+24
    const int rbase = wave * ROWS_PER_WAVE;

    if (f32) {
        // Lane l owns fp32 channels 4l..4l+3: one float4/lane = 1KB coalesced
        // wave-load per row. Continuous 50-row stream through ping-pong u0/u1
        // (<=2 batches = 64 VGPR live); merges interleave with loads; scores
        // go to scA/scB so no barrier is needed until both graphs are done.
        const vfloat4* xr = (const vfloat4*)xv;
        const vfloat4* bA = xr + (size_t)(gA * NPG + rbase) * (DIM / 4) + lane;
        const vfloat4* bB = xr + (size_t)((size_t)gB * NPG + rbase) * (DIM / 4) + lane;
        vfloat4 u0[8], u1[8], uA24, uB24;
        float p[8];

        load8(u0, bA, 0);
        load8(u1, bA, 8);
        dot8(p, u0, wl0, wl1, wl2, wl3);         // frees u0
        load8(u0, bA, 16);
        uA24 = __builtin_nontemporal_load(bA + (size_t)24 * (DIM / 4));
        { const float m = merge8(p, lane); if (lane < 8) scA[rbase + lane] = m + bval; }

        dot8(p, u1, wl0, wl1, wl2, wl3);         // frees u1
        if (hasB) load8(u1, bB, 0);
        { const float m = merge8(p, lane); if (lane < 8) scA[rbase + 8 + lane] = m + bval; }

        dot8(p, u0, wl0, wl1, wl2, wl3);         // frees u0
        if (hasB) load8(u0, bB, 8);
        { const float m = merge8(p, lane); if (lane < 8) scA[rbase + 16 + lane] = m + bval; }

        {   // A row 24
            float acc = uA24.x * wl0 + uA24.y * wl1 + uA24.z * wl2 + uA24.w * wl3;
            #pragma unroll
            for (int off = 32; off > 0; off >>= 1)
                acc += __shfl_xor(acc, off, 64);
            if (lane == 0) scA[rbase + 24] = acc + bval;
        }

        if (hasB) {
            dot8(p, u1, wl0, wl1, wl2, wl3);     // B batch 0; frees u1
            load8(u1, bB, 16);
            uB24 = __builtin_nontemporal_load(bB + (size_t)24 * (DIM / 4));
            { const float m = merge8(p, lane); if (lane < 8) scB[rbase + lane] = m + bval; }

            dot8(p, u0, wl0, wl1, wl2, wl3);     // B batch 1
            { const float m = merge8(p, lane); if (lane < 8) scB[rbase + 8 + lane] = m + bval; }

            dot8(p, u1, wl0, wl1, wl2, wl3);     // B batch 2
            { const float m = merge8(p, lane); if (lane < 8) scB[rbase + 16 + lane] = m + bval; }

            {   // B row 24
                float acc = uB24.x * wl0 + uB24.y * wl1 + uB24.z * wl2 + uB24.w * wl3;
                #pragma unroll
                for (int off = 32; off > 0; off >>= 1)
                    acc += __shfl_xor(acc, off, 64);
                if (lane == 0) scB[rbase + 24] = acc + bval;
            }
        }
    } else {
        // bf16: ushort4 = 8B/lane/row (2 VGPR) — keep all 25, per graph.
        const unsigned short* x = (const unsigned short*)xv;
        for (int gg = 0; gg < (hasB ? 2 : 1); ++gg) {
            const int g = gA + gg;
            float* scb = gg ? scB : scA;
            ushort4 u[ROWS_PER_WAVE];
            float p[ROWS_PER_WAVE];
            #pragma unroll
            for (int i = 0; i < ROWS_PER_WAVE; ++i)
                u[i] = ((const ushort4*)(x + (size_t)(g * NPG + rbase + i) * DIM))[lane];
            #pragma unroll
            for (int i = 0; i < ROWS_PER_WAVE; ++i)
                p[i] = bf2f(u[i].x) * wl0 + bf2f(u[i].y) * wl1
                     + bf2f(u[i].z) * wl2 + bf2f(u[i].w) * wl3;
            #pragma unroll
            for (int b = 0; b < 3; ++b) {
                const float m = merge8(&p[b * 8], lane);
                if (lane < 8) scb[rbase + b * 8 + lane] = m + bval;
            }
            {
                float acc = p[24];
                #pragma unroll
                for (int off = 32; off > 0; off >>= 1)
                    acc += __shfl_xor(acc, off, 64);
                if (lane == 0) scb[rbase + 24] = acc + bval;
            }
        }
    }
    __syncthreads();

    // Parallel selects: tid 0..99 rank graph A; tid 128..227 rank graph B.
    // rank = #{ i : v_i > v_j or (v_i == v_j and i < j) }  (== lax.top_k order)
    const bool doA = (tid < NPG);
    const bool doB = hasB && (tid >= 128) && (tid < 128 + NPG);
    if (doA || doB) {
        const float* sc = doA ? scA : scB;
        const int    t  = doA ? tid : (tid - 128);
        const int    g  = doA ? gA  : gB;
        const float v = sc[t];
        int rank = 0;
        #pragma unroll 4
        for (int i = 0; i < NPG; ++i) {
            const float vi = sc[i];
            rank += (vi > v) || (vi == v && i < t);
        }
        if (rank < KSEL) {
            const int total = num_graphs * KSEL;
            const int pos   = g * KSEL + rank;
            const int node  = g * NPG + t;
            if (f32) {
                float* o = (float*)outv;
                o[pos]             = (float)node;  // node_index
                o[total + pos]     = (float)pos;   // cluster_index
                o[2 * total + pos] = v;            // weight
            } else {
                __hip_bfloat16* o = (__hip_bfloat16*)outv;
                o[pos]             = __float2bfloat16((float)node);
                o[total + pos]     = __float2bfloat16((float)pos);
                o[2 * total + pos] = __float2bfloat16(v);
            }
        }
    }
}

extern "C" void kernel_launch(void* const* d_in, const int* in_sizes, int n_in,
                              void* d_out, int out_size, void* d_ws, size_t ws_size,
                              hipStream_t stream) {
    // Identify inputs by element count (dtype-invariant):
    //   x: largest tensor; W: exactly DIM elements; b: exactly 1 element.
    int xi = -1, wi = -1, bi = -1;
    long best = -1;
    for (int i = 0; i < n_in; ++i) {
        const long s = in_sizes[i];
        if (s > best) { best = s; xi = i; }
    }
    for (int i = 0; i < n_in; ++i) {
        if (i == xi) continue;
        const long s = in_sizes[i];
        if (s == DIM && wi < 0) wi = i;
        if (s == 1   && bi < 0) bi = i;
    }
    if (xi < 0) xi = 0;
    if (wi < 0) wi = (n_in > 2) ? 2 : 1;
    if (bi < 0) bi = n_in - 1;

    const long n_rows     = (long)in_sizes[xi] / DIM;   // 100000
    const long num_graphs = n_rows / NPG;               // 1000
    if (num_graphs <= 0) return;

    // d_ws deliberately unused (R8 proved the 400MB poison fills are
    // unconditional; not touching ws keeps the kernel side minimal).
    (void)d_ws; (void)ws_size;

    const unsigned nblocks = (unsigned)((num_graphs + 1) / 2);   // 2 graphs/block
    fused_select_kernel<<<dim3(nblocks), dim3(256), 0, stream>>>(
        d_in[xi], d_in[wi], d_in[bi], d_out, (int)num_graphs);
}